// Round 1
// baseline (1885.089 us; speedup 1.0000x reference)
//
#include <hip/hip_runtime.h>
#include <hip/hip_bf16.h>
#include <math.h>

#define BATCH 8
#define CDIM 512
#define HGT 96
#define WID 96
#define HWN (HGT*WID)          // 9216
#define INNER 256
#define NHEADS 8
#define DH 32
#define NPIX (BATCH*HWN)       // 73728
#define EPSLN 1e-5f
#define QSCALE 0.17677669529663687f

// ---------------- per-pixel channel-LN stats (mean, rstd over 512 chans) ----------------
__global__ __launch_bounds__(256) void stats512_kernel(const float* __restrict__ x,
                                                       float* __restrict__ mean,
                                                       float* __restrict__ rstd) {
    int p = blockIdx.x * 256 + threadIdx.x;      // pixel index over B*HW
    int b = p / HWN, n = p % HWN;
    const float* base = x + ((size_t)b * CDIM) * HWN + n;
    float s = 0.f, s2 = 0.f;
    for (int c = 0; c < CDIM; ++c) {
        float v = base[(size_t)c * HWN];
        s += v; s2 += v * v;
    }
    float m = s * (1.0f / CDIM);
    float var = s2 * (1.0f / CDIM) - m * m;      // biased variance (jnp.var default)
    mean[p] = m;
    rstd[p] = rsqrtf(var + EPSLN);
}

// ---------------- wsum[o] = sum_c W[o][c]*g[c]  for the three qkv weight sets ----------------
__global__ __launch_bounds__(256) void wsum_kernel(const float* __restrict__ qw,
                                                   const float* __restrict__ kw,
                                                   const float* __restrict__ vw,
                                                   const float* __restrict__ g,
                                                   float* __restrict__ wsum) {
    int i = blockIdx.x * 256 + threadIdx.x;      // 0..767
    if (i >= 3 * INNER) return;
    const float* w = (i < INNER) ? qw : (i < 2 * INNER) ? kw : vw;
    int o = i % INNER;
    float s = 0.f;
    for (int c = 0; c < CDIM; ++c) s += w[o * CDIM + c] * g[c];
    wsum[i] = s;
}

// ---------------- conv1x1 GEMM, optional fused input channel-LN ----------------
// Y[b][o][n] = (LN) rstd[p]*( sum_c W[o][c]*g[c]*X[b][c][n] - mean[p]*wsum[o] )
//             (else) sum_c W[o][c]*X[b][c][n]
// Tiles: BM=64, BN=64, BK=16; 256 threads, 4x4 micro-tile.
template <int MROWS, int KC, bool LN>
__global__ __launch_bounds__(256) void conv1x1_kernel(const float* __restrict__ X,
                                                      const float* __restrict__ W,
                                                      const float* __restrict__ g,
                                                      const float* __restrict__ mean,
                                                      const float* __restrict__ rstd,
                                                      const float* __restrict__ wsum,
                                                      float* __restrict__ Y) {
    __shared__ float Wt[16][68];   // [kk][r], row stride 68 (16B aligned, 2-way bank max)
    __shared__ float Xt[16][68];   // [kk][col]
    int b  = blockIdx.z;
    int n0 = blockIdx.x * 64;
    int o0 = blockIdx.y * 64;
    int tid = threadIdx.x;
    int tx = tid & 15, ty = tid >> 4;
    float acc[4][4] = {};
    const float* Xb = X + (size_t)b * KC * HWN;

    for (int c0 = 0; c0 < KC; c0 += 16) {
        {   // stage X tile: 16 rows x 64 cols, coalesced
            int col = tid & 63, row = tid >> 6;
            #pragma unroll
            for (int i = 0; i < 4; ++i)
                Xt[row + 4 * i][col] = Xb[(size_t)(c0 + row + 4 * i) * HWN + n0 + col];
        }
        {   // stage W tile (x g if LN): Wt[kk][r]
            int kk = tid & 15, r = tid >> 4;
            float gv = LN ? g[c0 + kk] : 1.0f;
            #pragma unroll
            for (int i = 0; i < 4; ++i)
                Wt[kk][r + 16 * i] = W[(size_t)(o0 + r + 16 * i) * KC + c0 + kk] * gv;
        }
        __syncthreads();
        #pragma unroll
        for (int kk = 0; kk < 16; ++kk) {
            float wv[4], xv[4];
            #pragma unroll
            for (int i = 0; i < 4; ++i) wv[i] = Wt[kk][ty * 4 + i];
            #pragma unroll
            for (int j = 0; j < 4; ++j) xv[j] = Xt[kk][tx * 4 + j];
            #pragma unroll
            for (int i = 0; i < 4; ++i)
                #pragma unroll
                for (int j = 0; j < 4; ++j)
                    acc[i][j] += wv[i] * xv[j];
        }
        __syncthreads();
    }

    #pragma unroll
    for (int i = 0; i < 4; ++i) {
        int o = o0 + ty * 4 + i;
        float ws_o = LN ? wsum[o] : 0.0f;
        size_t yb = ((size_t)b * MROWS + o) * HWN + n0 + tx * 4;
        #pragma unroll
        for (int j = 0; j < 4; ++j) {
            float v = acc[i][j];
            if (LN) {
                int p = b * HWN + n0 + tx * 4 + j;
                v = rstd[p] * (v - mean[p] * ws_o);
            }
            Y[yb + j] = v;
        }
    }
}

// ---------------- depthwise 3x3 SAME ----------------
__global__ __launch_bounds__(256) void dwconv_kernel(const float* __restrict__ X,
                                                     const float* __restrict__ Wd,
                                                     float* __restrict__ Y) {
    size_t i = (size_t)blockIdx.x * 256 + threadIdx.x;  // over B*INNER*HW
    int n = (int)(i % HWN);
    int bc = (int)(i / HWN);
    int c = bc % INNER;
    int y = n / WID, x = n % WID;
    const float* base = X + (size_t)bc * HWN;
    const float* wf = Wd + c * 9;
    float acc = 0.f;
    #pragma unroll
    for (int dy = 0; dy < 3; ++dy) {
        int yy = y + dy - 1;
        if ((unsigned)yy < HGT) {
            #pragma unroll
            for (int dx = 0; dx < 3; ++dx) {
                int xx = x + dx - 1;
                if ((unsigned)xx < WID) acc += base[yy * WID + xx] * wf[dy * 3 + dx];
            }
        }
    }
    Y[i] = acc;
}

// ---------------- q softmax over feature dim (32 chans within head), x scale, in-place ----------------
__global__ __launch_bounds__(256) void qsoftmax_kernel(float* __restrict__ Q) {
    size_t i = (size_t)blockIdx.x * 256 + threadIdx.x;  // over B*NHEADS*HW
    int n = (int)(i % HWN);
    int bh = (int)(i / HWN);
    int b = bh / NHEADS, h = bh % NHEADS;
    float* base = Q + ((size_t)b * INNER + h * DH) * HWN + n;
    float v[DH];
    float mx = -1e30f;
    #pragma unroll
    for (int d = 0; d < DH; ++d) { v[d] = base[(size_t)d * HWN]; mx = fmaxf(mx, v[d]); }
    float s = 0.f;
    #pragma unroll
    for (int d = 0; d < DH; ++d) { v[d] = __expf(v[d] - mx); s += v[d]; }
    float inv = QSCALE / s;
    #pragma unroll
    for (int d = 0; d < DH; ++d) base[(size_t)d * HWN] = v[d] * inv;
}

// ---------------- k softmax over spatial dim (9216), per (b, chan), in-place ----------------
__global__ __launch_bounds__(256) void ksoftmax_kernel(float* __restrict__ K) {
    int row = blockIdx.x;                    // b*INNER + c
    float* base = K + (size_t)row * HWN;
    int tid = threadIdx.x;
    __shared__ float red[256];
    float mx = -1e30f;
    for (int n = tid; n < HWN; n += 256) mx = fmaxf(mx, base[n]);
    red[tid] = mx; __syncthreads();
    for (int s = 128; s > 0; s >>= 1) { if (tid < s) red[tid] = fmaxf(red[tid], red[tid + s]); __syncthreads(); }
    mx = red[0]; __syncthreads();
    float sum = 0.f;
    for (int n = tid; n < HWN; n += 256) sum += __expf(base[n] - mx);
    red[tid] = sum; __syncthreads();
    for (int s = 128; s > 0; s >>= 1) { if (tid < s) red[tid] += red[tid + s]; __syncthreads(); }
    float inv = 1.0f / red[0];
    for (int n = tid; n < HWN; n += 256) base[n] = __expf(base[n] - mx) * inv;
}

// ---------------- context partials: ctxp[bh][seg][d][e] = sum_{n in seg} k[d][n]*v[e][n] ----------------
__global__ __launch_bounds__(256) void context_kernel(const float* __restrict__ K,
                                                      const float* __restrict__ V,
                                                      float* __restrict__ ctxp) {
    int seg = blockIdx.x;                    // 0..15, each covers 576 n
    int bh = blockIdx.y;
    int b = bh / NHEADS, h = bh % NHEADS;
    const float* kb = K + ((size_t)b * INNER + h * DH) * HWN;
    const float* vb = V + ((size_t)b * INNER + h * DH) * HWN;
    __shared__ float kt[DH][64];
    __shared__ float vt[DH][65];
    int tid = threadIdx.x;
    int e = tid & 31;
    int d0 = tid >> 5;                       // 0..7; this thread owns d = d0 + 8*i
    float acc[4] = {0.f, 0.f, 0.f, 0.f};
    for (int ch = 0; ch < 9; ++ch) {
        int n0 = seg * 576 + ch * 64;
        __syncthreads();
        #pragma unroll
        for (int j = 0; j < 8; ++j) {
            int idx = tid + 256 * j;         // 0..2047
            int d = idx >> 6, nn = idx & 63;
            kt[d][nn] = kb[(size_t)d * HWN + n0 + nn];
            vt[d][nn] = vb[(size_t)d * HWN + n0 + nn];
        }
        __syncthreads();
        for (int nn = 0; nn < 64; ++nn) {
            float vv = vt[e][nn];
            #pragma unroll
            for (int i = 0; i < 4; ++i) acc[i] += kt[d0 + 8 * i][nn] * vv;
        }
    }
    #pragma unroll
    for (int i = 0; i < 4; ++i)
        ctxp[(((size_t)bh * 16 + seg) * DH + d0 + 8 * i) * DH + e] = acc[i];
}

__global__ __launch_bounds__(256) void ctxreduce_kernel(const float* __restrict__ ctxp,
                                                        float* __restrict__ ctx) {
    int i = blockIdx.x * 256 + threadIdx.x;  // over 64*1024
    int bh = i >> 10, de = i & 1023;
    float s = 0.f;
    #pragma unroll
    for (int seg = 0; seg < 16; ++seg) s += ctxp[((size_t)bh * 16 + seg) * 1024 + de];
    ctx[i] = s;
}

// ---------------- out = silu(q @ ctx), written back in [B][INNER][HW] layout ----------------
__global__ __launch_bounds__(256) void qctx_kernel(const float* __restrict__ Q,
                                                   const float* __restrict__ ctx,
                                                   float* __restrict__ O) {
    int bh = blockIdx.y;
    int b = bh / NHEADS, h = bh % NHEADS;
    int n = blockIdx.x * 256 + threadIdx.x;
    __shared__ float cs[DH * DH];
    for (int j = threadIdx.x; j < DH * DH; j += 256) cs[j] = ctx[(size_t)bh * DH * DH + j];
    __syncthreads();
    const float* qb = Q + ((size_t)b * INNER + h * DH) * HWN + n;
    float acc[DH];
    #pragma unroll
    for (int e = 0; e < DH; ++e) acc[e] = 0.f;
    #pragma unroll
    for (int d = 0; d < DH; ++d) {
        float qv = qb[(size_t)d * HWN];
        #pragma unroll
        for (int e = 0; e < DH; ++e) acc[e] += qv * cs[d * DH + e];
    }
    float* ob = O + ((size_t)b * INNER + h * DH) * HWN + n;
    #pragma unroll
    for (int e = 0; e < DH; ++e) {
        float x = acc[e];
        ob[(size_t)e * HWN] = x / (1.0f + __expf(-x));  // silu
    }
}

// ---------------- final normalize: out = (x - mean)*rstd*g ----------------
__global__ __launch_bounds__(256) void norm_kernel(const float* __restrict__ X,
                                                   const float* __restrict__ mean,
                                                   const float* __restrict__ rstd,
                                                   const float* __restrict__ g,
                                                   float* __restrict__ out) {
    size_t i = (size_t)blockIdx.x * 256 + threadIdx.x;  // over B*CDIM*HW
    int n = (int)(i % HWN);
    size_t bc = i / HWN;
    int c = (int)(bc % CDIM);
    int b = (int)(bc / CDIM);
    int p = b * HWN + n;
    out[i] = (X[i] - mean[p]) * rstd[p] * g[c];
}

extern "C" void kernel_launch(void* const* d_in, const int* in_sizes, int n_in,
                              void* d_out, int out_size, void* d_ws, size_t ws_size,
                              hipStream_t stream) {
    const float* fmap      = (const float*)d_in[0];
    const float* norm_g    = (const float*)d_in[1];
    const float* q_w1      = (const float*)d_in[2];
    const float* q_wd      = (const float*)d_in[3];
    const float* k_w1      = (const float*)d_in[4];
    const float* k_wd      = (const float*)d_in[5];
    const float* v_w1      = (const float*)d_in[6];
    const float* v_wd      = (const float*)d_in[7];
    const float* out_w     = (const float*)d_in[8];
    const float* out_norm_g= (const float*)d_in[9];
    float* out = (float*)d_out;

    float* ws = (float*)d_ws;
    // workspace layout (floats); total = 76,907,264 floats = 307.6 MB
    float* mean1 = ws;                         // 73728
    float* rstd1 = ws + 73728;                 // 73728
    float* mean2 = ws + 147456;                // 73728
    float* rstd2 = ws + 221184;                // 73728
    float* wsum  = ws + 294912;                // 768
    float* ctxp  = ws + 295680;                // 64*16*1024 = 1048576
    float* ctx   = ws + 1344256;               // 65536
    float* A     = ws + 1409792;               // 18874368 (conv tmp, later attn_out)
    float* QD    = ws + 20284160;              // 18874368
    float* KD    = ws + 39158528;              // 18874368
    float* VD    = ws + 58032896;              // 18874368
    float* CONV2 = QD;                         // 37748736 (reuses QD+KD after they're dead)

    dim3 blk(256);
    dim3 gStats(NPIX / 256);
    dim3 gGemm1(HWN / 64, INNER / 64, BATCH);
    dim3 gGemm2(HWN / 64, CDIM / 64, BATCH);
    dim3 gDw((BATCH * INNER * HWN) / 256);
    dim3 gQsm((BATCH * NHEADS * HWN) / 256);
    dim3 gKsm(BATCH * INNER);
    dim3 gCtx(16, BATCH * NHEADS);
    dim3 gCtxR(64 * 1024 / 256);
    dim3 gQC(HWN / 256, BATCH * NHEADS);
    dim3 gNorm((BATCH * CDIM * HWN) / 256);

    stats512_kernel<<<gStats, blk, 0, stream>>>(fmap, mean1, rstd1);
    wsum_kernel<<<dim3(3), blk, 0, stream>>>(q_w1, k_w1, v_w1, norm_g, wsum);

    conv1x1_kernel<INNER, CDIM, true><<<gGemm1, blk, 0, stream>>>(fmap, q_w1, norm_g, mean1, rstd1, wsum, A);
    dwconv_kernel<<<gDw, blk, 0, stream>>>(A, q_wd, QD);
    conv1x1_kernel<INNER, CDIM, true><<<gGemm1, blk, 0, stream>>>(fmap, k_w1, norm_g, mean1, rstd1, wsum + INNER, A);
    dwconv_kernel<<<gDw, blk, 0, stream>>>(A, k_wd, KD);
    conv1x1_kernel<INNER, CDIM, true><<<gGemm1, blk, 0, stream>>>(fmap, v_w1, norm_g, mean1, rstd1, wsum + 2 * INNER, A);
    dwconv_kernel<<<gDw, blk, 0, stream>>>(A, v_wd, VD);

    qsoftmax_kernel<<<gQsm, blk, 0, stream>>>(QD);
    ksoftmax_kernel<<<gKsm, blk, 0, stream>>>(KD);

    context_kernel<<<gCtx, blk, 0, stream>>>(KD, VD, ctxp);
    ctxreduce_kernel<<<gCtxR, blk, 0, stream>>>(ctxp, ctx);
    qctx_kernel<<<gQC, blk, 0, stream>>>(QD, ctx, A);      // A = silu(attn out)

    conv1x1_kernel<CDIM, INNER, false><<<gGemm2, blk, 0, stream>>>(A, out_w, nullptr, nullptr, nullptr, nullptr, CONV2);
    stats512_kernel<<<gStats, blk, 0, stream>>>(CONV2, mean2, rstd2);
    norm_kernel<<<gNorm, blk, 0, stream>>>(CONV2, mean2, rstd2, out_norm_g, out);
}

// Round 3
// 1309.892 us; speedup vs baseline: 1.4391x; 1.4391x over previous
//
#include <hip/hip_runtime.h>
#include <math.h>

#define BATCH 8
#define GB 4              // batches per group (2 groups keeps peak ws ~194 MB)
#define CDIM 512
#define HGT 96
#define WID 96
#define HWN (HGT*WID)     // 9216
#define INNER 256
#define NHEADS 8
#define DH 32
#define NPIX (BATCH*HWN)
#define EPSLN 1e-5f
#define QSCALE 0.17677669529663687f

typedef __bf16 bf16_t;
typedef bf16_t bf16x8 __attribute__((ext_vector_type(8)));
typedef float  f32x4  __attribute__((ext_vector_type(4)));

__device__ __forceinline__ void load_lds16(const bf16_t* gp, bf16_t* lp) {
    __builtin_amdgcn_global_load_lds(
        (const __attribute__((address_space(1))) unsigned int*)gp,
        (__attribute__((address_space(3))) unsigned int*)lp,
        16, 0, 0);
}

// ---------------- per-pixel channel-LN stats over CDIM chans (grid-sized: works per-group too) ----
__global__ __launch_bounds__(256) void stats512_kernel(const float* __restrict__ x,
                                                       float* __restrict__ mean,
                                                       float* __restrict__ rstd) {
    int p = blockIdx.x * 256 + threadIdx.x;
    int b = p / HWN, n = p % HWN;
    const float* base = x + ((size_t)b * CDIM) * HWN + n;
    float s = 0.f, s2 = 0.f;
    for (int c = 0; c < CDIM; ++c) {
        float v = base[(size_t)c * HWN];
        s += v; s2 += v * v;
    }
    float m = s * (1.0f / CDIM);
    float var = s2 * (1.0f / CDIM) - m * m;
    mean[p] = m;
    rstd[p] = rsqrtf(var + EPSLN);
}

// ---------------- wsum[o] = sum_c W[o][c]*g[c] (fp32, exact algebra for LN fusion) --------------
__global__ __launch_bounds__(256) void wsum_kernel(const float* __restrict__ qw,
                                                   const float* __restrict__ kw,
                                                   const float* __restrict__ vw,
                                                   const float* __restrict__ g,
                                                   float* __restrict__ wsum) {
    int i = blockIdx.x * 256 + threadIdx.x;
    if (i >= 3 * INNER) return;
    const float* w = (i < INNER) ? qw : (i < 2 * INNER) ? kw : vw;
    int o = i % INNER;
    float s = 0.f;
    for (int c = 0; c < CDIM; ++c) s += w[o * CDIM + c] * g[c];
    wsum[i] = s;
}

// ---------------- weight prep: split (w*g) and out_w into bf16 hi/lo planes ---------------------
__global__ __launch_bounds__(256) void wprep_kernel(const float* __restrict__ qw,
                                                    const float* __restrict__ kw,
                                                    const float* __restrict__ vw,
                                                    const float* __restrict__ g,
                                                    const float* __restrict__ ow,
                                                    bf16_t* __restrict__ Wqh, bf16_t* __restrict__ Wql,
                                                    bf16_t* __restrict__ Wkh, bf16_t* __restrict__ Wkl,
                                                    bf16_t* __restrict__ Wvh, bf16_t* __restrict__ Wvl,
                                                    bf16_t* __restrict__ OWh, bf16_t* __restrict__ OWl) {
    int i = blockIdx.x * 256 + threadIdx.x;        // 0..524287
    if (i < 3 * INNER * CDIM) {
        int m = i / (INNER * CDIM);
        int idx = i % (INNER * CDIM);
        int c = idx % CDIM;
        const float* w = (m == 0) ? qw : (m == 1) ? kw : vw;
        float val = w[idx] * g[c];
        bf16_t h = (bf16_t)val;
        bf16_t l = (bf16_t)(val - (float)h);
        bf16_t* H = (m == 0) ? Wqh : (m == 1) ? Wkh : Wvh;
        bf16_t* L = (m == 0) ? Wql : (m == 1) ? Wkl : Wvl;
        H[idx] = h; L[idx] = l;
    } else {
        int idx = i - 3 * INNER * CDIM;            // 0..131071 over [512][256]
        float val = ow[idx];
        bf16_t h = (bf16_t)val;
        bf16_t l = (bf16_t)(val - (float)h);
        OWh[idx] = h; OWl[idx] = l;
    }
}

// ---------------- transpose+split: fmap [bb][c][n] fp32 -> Fh/Fl [bb][n][c] bf16 ----------------
__global__ __launch_bounds__(256) void transpose_split_kernel(const float* __restrict__ X,
                                                              bf16_t* __restrict__ Fh,
                                                              bf16_t* __restrict__ Fl) {
    __shared__ float T[64][65];
    int bb = blockIdx.z;
    int n0 = blockIdx.x * 64;
    int c0 = blockIdx.y * 64;
    const float* Xb = X + ((size_t)bb * CDIM) * HWN;
    int tid = threadIdx.x;
    int tx = tid & 63, ty = tid >> 6;
    #pragma unroll
    for (int cc = 0; cc < 64; cc += 4)
        T[cc + ty][tx] = Xb[(size_t)(c0 + cc + ty) * HWN + n0 + tx];
    __syncthreads();
    size_t obase = ((size_t)bb * HWN) * CDIM;
    #pragma unroll
    for (int nn = 0; nn < 64; nn += 4) {
        float v = T[tx][nn + ty];
        bf16_t h = (bf16_t)v;
        bf16_t l = (bf16_t)(v - (float)h);
        size_t off = obase + (size_t)(n0 + nn + ty) * CDIM + c0 + tx;
        Fh[off] = h; Fl[off] = l;
    }
}

// ---------------- split-bf16 3-pass MFMA GEMM: Y[bb][o][n] = sum_c Wg[o][c] * X[bb][n][c] -------
// A (weights) [MROWS][KDIM] hi/lo; B (acts) [GB][HWN][KDIM] hi/lo; optional fused input-LN epilogue.
// 128x128 tile, BK=32, 256 threads (4 waves, 2x2), 4x4 16x16x32 MFMAs per wave, 3 passes (hh,hl,lh).
template <int KDIM, int MROWS, bool LN>
__global__ __launch_bounds__(256) void mfma_gemm_kernel(const bf16_t* __restrict__ Ah,
                                                        const bf16_t* __restrict__ Al,
                                                        const bf16_t* __restrict__ Bh,
                                                        const bf16_t* __restrict__ Bl,
                                                        const float* __restrict__ mean,
                                                        const float* __restrict__ rstd,
                                                        const float* __restrict__ wsum,
                                                        int pbase,
                                                        float* __restrict__ Y) {
    __shared__ bf16_t sA[2][128 * 32];   // hi/lo, 8 KB each
    __shared__ bf16_t sB[2][128 * 32];
    int bb = blockIdx.z;
    int n0 = blockIdx.x * 128;
    int o0 = blockIdx.y * 128;
    int tid = threadIdx.x;
    int wv = tid >> 6, ln = tid & 63;
    int wm = wv >> 1, wn = wv & 1;
    int quad = ln >> 4, lm = ln & 15;
    int srow = ln >> 2;            // staging row within 16
    int scol = (ln & 3) * 8;       // staging col (bf16 units)

    const bf16_t* Bhb = Bh + ((size_t)bb * HWN) * KDIM;
    const bf16_t* Blb = Bl + ((size_t)bb * HWN) * KDIM;

    f32x4 acc[4][4] = {};

    for (int c0 = 0; c0 < KDIM; c0 += 32) {
        __syncthreads();
        #pragma unroll
        for (int t = 0; t < 2; ++t) {
            int inst = wv * 2 + t;
            int row = inst * 16 + srow;
            size_t goA = (size_t)(o0 + row) * KDIM + c0 + scol;
            size_t goB = (size_t)(n0 + row) * KDIM + c0 + scol;
            load_lds16(&Ah[goA],  &sA[0][inst * 512]);
            load_lds16(&Al[goA],  &sA[1][inst * 512]);
            load_lds16(&Bhb[goB], &sB[0][inst * 512]);
            load_lds16(&Blb[goB], &sB[1][inst * 512]);
        }
        __syncthreads();   // compiler inserts vmcnt(0) drain before barrier

        bf16x8 afh[4], afl[4], bfh[4], bfl[4];
        #pragma unroll
        for (int i = 0; i < 4; ++i) {
            int o_l = wm * 64 + i * 16 + lm;
            afh[i] = *(const bf16x8*)&sA[0][o_l * 32 + quad * 8];
            afl[i] = *(const bf16x8*)&sA[1][o_l * 32 + quad * 8];
            int n_l = wn * 64 + i * 16 + lm;
            bfh[i] = *(const bf16x8*)&sB[0][n_l * 32 + quad * 8];
            bfl[i] = *(const bf16x8*)&sB[1][n_l * 32 + quad * 8];
        }
        #pragma unroll
        for (int i = 0; i < 4; ++i)
            #pragma unroll
            for (int j = 0; j < 4; ++j) {
                acc[i][j] = __builtin_amdgcn_mfma_f32_16x16x32_bf16(afh[i], bfh[j], acc[i][j], 0, 0, 0);
                acc[i][j] = __builtin_amdgcn_mfma_f32_16x16x32_bf16(afh[i], bfl[j], acc[i][j], 0, 0, 0);
                acc[i][j] = __builtin_amdgcn_mfma_f32_16x16x32_bf16(afl[i], bfh[j], acc[i][j], 0, 0, 0);
            }
    }

    float* Yb = Y + ((size_t)bb * MROWS) * HWN;
    #pragma unroll
    for (int j = 0; j < 4; ++j) {
        int n = n0 + wn * 64 + j * 16 + lm;
        float mn = 0.f, rs = 0.f;
        if (LN) {
            int p = pbase + bb * HWN + n;
            mn = mean[p]; rs = rstd[p];
        }
        #pragma unroll
        for (int i = 0; i < 4; ++i) {
            #pragma unroll
            for (int r = 0; r < 4; ++r) {
                int o = o0 + wm * 64 + i * 16 + quad * 4 + r;
                float v = acc[i][j][r];
                if (LN) v = rs * (v - mn * wsum[o]);
                Yb[(size_t)o * HWN + n] = v;
            }
        }
    }
}

// ---------------- depthwise 3x3 SAME (group-local: GB batches) ----------------------------------
__global__ __launch_bounds__(256) void dwconv_kernel(const float* __restrict__ X,
                                                     const float* __restrict__ Wd,
                                                     float* __restrict__ Y) {
    size_t i = (size_t)blockIdx.x * 256 + threadIdx.x;  // over GB*INNER*HW
    int n = (int)(i % HWN);
    int bc = (int)(i / HWN);
    int c = bc % INNER;
    int y = n / WID, x = n % WID;
    const float* base = X + (size_t)bc * HWN;
    const float* wf = Wd + c * 9;
    float acc = 0.f;
    #pragma unroll
    for (int dy = 0; dy < 3; ++dy) {
        int yy = y + dy - 1;
        if ((unsigned)yy < HGT) {
            #pragma unroll
            for (int dx = 0; dx < 3; ++dx) {
                int xx = x + dx - 1;
                if ((unsigned)xx < WID) acc += base[yy * WID + xx] * wf[dy * 3 + dx];
            }
        }
    }
    Y[i] = acc;
}

// ---------------- k softmax over spatial dim, online (2 read passes + 1 write) ------------------
__global__ __launch_bounds__(256) void ksoftmax_kernel(float* __restrict__ K) {
    int row = blockIdx.x;                    // bb*INNER + c
    float* base = K + (size_t)row * HWN;
    int tid = threadIdx.x;
    __shared__ float rm[256], rs[256];
    float m = -1e30f, s = 0.f;
    for (int n = tid; n < HWN; n += 256) {
        float v = base[n];
        float nm = fmaxf(m, v);
        s = s * __expf(m - nm) + __expf(v - nm);
        m = nm;
    }
    rm[tid] = m; rs[tid] = s; __syncthreads();
    for (int st = 128; st > 0; st >>= 1) {
        if (tid < st) {
            float m2 = rm[tid + st], s2 = rs[tid + st];
            float nm = fmaxf(rm[tid], m2);
            rs[tid] = rs[tid] * __expf(rm[tid] - nm) + s2 * __expf(m2 - nm);
            rm[tid] = nm;
        }
        __syncthreads();
    }
    float M = rm[0], inv = 1.0f / rs[0];
    for (int n = tid; n < HWN; n += 256) base[n] = __expf(base[n] - M) * inv;
}

// ---------------- context partials: ctxp[bh][seg][d][e] = sum_{n in seg} k[d][n]*v[e][n] --------
__global__ __launch_bounds__(256) void context_kernel(const float* __restrict__ K,
                                                      const float* __restrict__ V,
                                                      float* __restrict__ ctxp) {
    int seg = blockIdx.x;                    // 0..15
    int bh = blockIdx.y;                     // 0..GB*NHEADS-1
    int bb = bh / NHEADS, h = bh % NHEADS;
    const float* kb = K + ((size_t)bb * INNER + h * DH) * HWN;
    const float* vb = V + ((size_t)bb * INNER + h * DH) * HWN;
    __shared__ float kt[DH][64];
    __shared__ float vt[DH][65];
    int tid = threadIdx.x;
    int e = tid & 31;
    int d0 = tid >> 5;
    float acc[4] = {0.f, 0.f, 0.f, 0.f};
    for (int ch = 0; ch < 9; ++ch) {
        int n0 = seg * 576 + ch * 64;
        __syncthreads();
        #pragma unroll
        for (int j = 0; j < 8; ++j) {
            int idx = tid + 256 * j;
            int d = idx >> 6, nn = idx & 63;
            kt[d][nn] = kb[(size_t)d * HWN + n0 + nn];
            vt[d][nn] = vb[(size_t)d * HWN + n0 + nn];
        }
        __syncthreads();
        for (int nn = 0; nn < 64; ++nn) {
            float vv = vt[e][nn];
            #pragma unroll
            for (int i = 0; i < 4; ++i) acc[i] += kt[d0 + 8 * i][nn] * vv;
        }
    }
    #pragma unroll
    for (int i = 0; i < 4; ++i)
        ctxp[(((size_t)bh * 16 + seg) * DH + d0 + 8 * i) * DH + e] = acc[i];
}

__global__ __launch_bounds__(256) void ctxreduce_kernel(const float* __restrict__ ctxp,
                                                        float* __restrict__ ctx) {
    int i = blockIdx.x * 256 + threadIdx.x;  // over GB*NHEADS*1024
    int bh = i >> 10, de = i & 1023;
    float s = 0.f;
    #pragma unroll
    for (int seg = 0; seg < 16; ++seg) s += ctxp[((size_t)bh * 16 + seg) * 1024 + de];
    ctx[i] = s;
}

// ---------------- fused q-softmax + q@ctx + silu, writes Oh/Ol [bb][n][INNER] bf16 hi/lo --------
__global__ __launch_bounds__(256) void qctx_kernel(const float* __restrict__ Q,
                                                   const float* __restrict__ ctx,
                                                   bf16_t* __restrict__ Oh,
                                                   bf16_t* __restrict__ Ol) {
    int bh = blockIdx.y;
    int bb = bh / NHEADS, h = bh % NHEADS;
    int n = blockIdx.x * 256 + threadIdx.x;
    __shared__ float cs[DH * DH];
    for (int j = threadIdx.x; j < DH * DH; j += 256) cs[j] = ctx[(size_t)bh * DH * DH + j];
    __syncthreads();
    const float* qb = Q + ((size_t)bb * INNER + h * DH) * HWN + n;
    float qv[DH];
    float mx = -1e30f;
    #pragma unroll
    for (int d = 0; d < DH; ++d) { qv[d] = qb[(size_t)d * HWN]; mx = fmaxf(mx, qv[d]); }
    float s = 0.f;
    #pragma unroll
    for (int d = 0; d < DH; ++d) { qv[d] = __expf(qv[d] - mx); s += qv[d]; }
    float inv = QSCALE / s;
    float acc[DH];
    #pragma unroll
    for (int e = 0; e < DH; ++e) acc[e] = 0.f;
    #pragma unroll
    for (int d = 0; d < DH; ++d) {
        float q = qv[d] * inv;
        #pragma unroll
        for (int e = 0; e < DH; ++e) acc[e] += q * cs[d * DH + e];
    }
    size_t ob = ((size_t)bb * HWN + n) * INNER + h * DH;
    bf16x8 hv, lv;
    #pragma unroll
    for (int e8 = 0; e8 < 4; ++e8) {
        #pragma unroll
        for (int e = 0; e < 8; ++e) {
            float x = acc[e8 * 8 + e];
            float sl = x / (1.0f + __expf(-x));   // silu
            bf16_t h = (bf16_t)sl;
            hv[e] = h;
            lv[e] = (bf16_t)(sl - (float)h);
        }
        *(bf16x8*)&Oh[ob + e8 * 8] = hv;
        *(bf16x8*)&Ol[ob + e8 * 8] = lv;
    }
}

// ---------------- final normalize (group-local) -------------------------------------------------
__global__ __launch_bounds__(256) void norm_kernel(const float* __restrict__ X,
                                                   const float* __restrict__ mean,
                                                   const float* __restrict__ rstd,
                                                   const float* __restrict__ g,
                                                   float* __restrict__ out) {
    size_t i = (size_t)blockIdx.x * 256 + threadIdx.x;  // over GB*CDIM*HW
    int n = (int)(i % HWN);
    size_t bc = i / HWN;
    int c = (int)(bc % CDIM);
    int bb = (int)(bc / CDIM);
    int p = bb * HWN + n;
    out[i] = (X[i] - mean[p]) * rstd[p] * g[c];
}

extern "C" void kernel_launch(void* const* d_in, const int* in_sizes, int n_in,
                              void* d_out, int out_size, void* d_ws, size_t ws_size,
                              hipStream_t stream) {
    const float* fmap       = (const float*)d_in[0];
    const float* norm_g     = (const float*)d_in[1];
    const float* q_w1       = (const float*)d_in[2];
    const float* q_wd       = (const float*)d_in[3];
    const float* k_w1       = (const float*)d_in[4];
    const float* k_wd       = (const float*)d_in[5];
    const float* v_w1       = (const float*)d_in[6];
    const float* v_wd       = (const float*)d_in[7];
    const float* out_w      = (const float*)d_in[8];
    const float* out_norm_g = (const float*)d_in[9];
    float* out = (float*)d_out;

    float* ws = (float*)d_ws;
    size_t off = 0;
    auto alloc = [&](size_t n) { float* p = ws + off; off += n; return p; };
    float* mean1 = alloc(73728);
    float* rstd1 = alloc(73728);
    float* mean2 = alloc(36864);
    float* rstd2 = alloc(36864);
    float* wsum  = alloc(768);
    bf16_t* Wqh = (bf16_t*)alloc(65536);   // 256*512 bf16 = 65536 floats
    bf16_t* Wql = (bf16_t*)alloc(65536);
    bf16_t* Wkh = (bf16_t*)alloc(65536);
    bf16_t* Wkl = (bf16_t*)alloc(65536);
    bf16_t* Wvh = (bf16_t*)alloc(65536);
    bf16_t* Wvl = (bf16_t*)alloc(65536);
    bf16_t* OWh = (bf16_t*)alloc(65536);   // FIX R2->R3: 512*256 bf16 = 65536 floats (was 32768)
    bf16_t* OWl = (bf16_t*)alloc(65536);   // FIX R2->R3: (was 32768 -> spilled into ctxp = NaN bf16 patterns)
    float* ctxp = alloc(524288);
    float* ctx  = alloc(32768);
    float* Fh_f = alloc(9437184);   // bf16 X-transpose hi (GB*HWN*CDIM bf16)
    float* Fl_f = alloc(9437184);   // lo
    float* A    = alloc(9437184);   // conv1x1 out fp32, GB*INNER*HWN
    float* KD   = alloc(9437184);
    float* VD   = alloc(9437184);
    // total ws use: 48,489,216 floats = 194.0 MB
    bf16_t* Fh = (bf16_t*)Fh_f;
    bf16_t* Fl = (bf16_t*)Fl_f;
    float* QD = Fh_f;                             // overlay: Fh dead after GEMMq
    bf16_t* Oh = (bf16_t*)Fl_f;                   // overlay: Fl dead after GEMMq
    bf16_t* Ol = Oh + (size_t)GB * HWN * INNER;
    float* CONV2 = A;                             // overlay [A][KD]: dead before final GEMM

    dim3 blk(256);
    stats512_kernel<<<dim3(NPIX / 256), blk, 0, stream>>>(fmap, mean1, rstd1);
    wsum_kernel<<<dim3(3), blk, 0, stream>>>(q_w1, k_w1, v_w1, norm_g, wsum);
    wprep_kernel<<<dim3(2048), blk, 0, stream>>>(q_w1, k_w1, v_w1, norm_g, out_w,
                                                 Wqh, Wql, Wkh, Wkl, Wvh, Wvl, OWh, OWl);

    for (int g = 0; g < 2; ++g) {
        const float* fmg = fmap + (size_t)g * GB * CDIM * HWN;
        int pbase = g * GB * HWN;
        transpose_split_kernel<<<dim3(144, 8, GB), blk, 0, stream>>>(fmg, Fh, Fl);

        // k path
        mfma_gemm_kernel<CDIM, INNER, true><<<dim3(72, 2, GB), blk, 0, stream>>>(
            Wkh, Wkl, Fh, Fl, mean1, rstd1, wsum + INNER, pbase, A);
        dwconv_kernel<<<dim3(GB * INNER * HWN / 256), blk, 0, stream>>>(A, k_wd, KD);
        ksoftmax_kernel<<<dim3(GB * INNER), blk, 0, stream>>>(KD);
        // v path
        mfma_gemm_kernel<CDIM, INNER, true><<<dim3(72, 2, GB), blk, 0, stream>>>(
            Wvh, Wvl, Fh, Fl, mean1, rstd1, wsum + 2 * INNER, pbase, A);
        dwconv_kernel<<<dim3(GB * INNER * HWN / 256), blk, 0, stream>>>(A, v_wd, VD);
        // q path (last use of Fh/Fl, then overlays become live)
        mfma_gemm_kernel<CDIM, INNER, true><<<dim3(72, 2, GB), blk, 0, stream>>>(
            Wqh, Wql, Fh, Fl, mean1, rstd1, wsum, pbase, A);
        dwconv_kernel<<<dim3(GB * INNER * HWN / 256), blk, 0, stream>>>(A, q_wd, QD);

        context_kernel<<<dim3(16, GB * NHEADS), blk, 0, stream>>>(KD, VD, ctxp);
        ctxreduce_kernel<<<dim3(GB * NHEADS * 1024 / 256), blk, 0, stream>>>(ctxp, ctx);
        qctx_kernel<<<dim3(HWN / 256, GB * NHEADS), blk, 0, stream>>>(QD, ctx, Oh, Ol);

        mfma_gemm_kernel<INNER, CDIM, false><<<dim3(72, 4, GB), blk, 0, stream>>>(
            OWh, OWl, Oh, Ol, nullptr, nullptr, nullptr, 0, CONV2);
        stats512_kernel<<<dim3(GB * HWN / 256), blk, 0, stream>>>(CONV2, mean2, rstd2);
        norm_kernel<<<dim3(GB * CDIM * HWN / 256), blk, 0, stream>>>(
            CONV2, mean2, rstd2, out_norm_g, out + (size_t)g * GB * CDIM * HWN);
    }
}

// Round 4
// 1170.111 us; speedup vs baseline: 1.6110x; 1.1195x over previous
//
#include <hip/hip_runtime.h>
#include <math.h>

#define BATCH 8
#define GB 4              // batches per group (2 groups)
#define CDIM 512
#define HGT 96
#define WID 96
#define HWN (HGT*WID)     // 9216
#define INNER 256
#define NHEADS 8
#define DH 32
#define NPIX (BATCH*HWN)
#define EPSLN 1e-5f
#define QSCALE 0.17677669529663687f
#define PATHSZ ((size_t)GB*INNER*HWN)   // 9,437,184 elements per qkv plane per group

typedef __bf16 bf16_t;
typedef bf16_t bf16x8 __attribute__((ext_vector_type(8)));
typedef float  f32x4  __attribute__((ext_vector_type(4)));

__device__ __forceinline__ void load_lds16(const bf16_t* gp, bf16_t* lp) {
    __builtin_amdgcn_global_load_lds(
        (const __attribute__((address_space(1))) unsigned int*)gp,
        (__attribute__((address_space(3))) unsigned int*)lp,
        16, 0, 0);
}

// ---------------- wsum[o] = sum_c W[o][c]*g[c] (fp32, exact algebra for LN fusion) --------------
__global__ __launch_bounds__(256) void wsum_kernel(const float* __restrict__ qw,
                                                   const float* __restrict__ kw,
                                                   const float* __restrict__ vw,
                                                   const float* __restrict__ g,
                                                   float* __restrict__ wsum) {
    int i = blockIdx.x * 256 + threadIdx.x;
    if (i >= 3 * INNER) return;
    const float* w = (i < INNER) ? qw : (i < 2 * INNER) ? kw : vw;
    int o = i % INNER;
    float s = 0.f;
    for (int c = 0; c < CDIM; ++c) s += w[o * CDIM + c] * g[c];
    wsum[i] = s;
}

// ---------------- weight prep: split (w*g) and out_w into bf16 hi/lo planes ---------------------
// WB layout (bf16): [path(q,k,v)][hi/lo][INNER*CDIM].  OWB: [hi/lo][CDIM*INNER].
__global__ __launch_bounds__(256) void wprep_kernel(const float* __restrict__ qw,
                                                    const float* __restrict__ kw,
                                                    const float* __restrict__ vw,
                                                    const float* __restrict__ g,
                                                    const float* __restrict__ ow,
                                                    bf16_t* __restrict__ WB,
                                                    bf16_t* __restrict__ OWB) {
    int i = blockIdx.x * 256 + threadIdx.x;        // 0..524287
    const int PS = INNER * CDIM;                   // 131072
    if (i < 3 * PS) {
        int m = i / PS;
        int idx = i % PS;
        int c = idx % CDIM;
        const float* w = (m == 0) ? qw : (m == 1) ? kw : vw;
        float val = w[idx] * g[c];
        bf16_t h = (bf16_t)val;
        bf16_t l = (bf16_t)(val - (float)h);
        WB[(size_t)(2 * m) * PS + idx] = h;
        WB[(size_t)(2 * m + 1) * PS + idx] = l;
    } else {
        int idx = i - 3 * PS;                      // 0..131071 over [512][256]
        float val = ow[idx];
        bf16_t h = (bf16_t)val;
        bf16_t l = (bf16_t)(val - (float)h);
        OWB[idx] = h;
        OWB[PS + idx] = l;
    }
}

// ---------------- transpose+split+stats: X [bb][c][n] fp32 -> Fh/Fl [bb][n][c] bf16 -------------
// Also accumulates per-pixel sum/sumsq into S1/S2 (LN stats, 8 c-tile contributions per pixel).
__global__ __launch_bounds__(256) void transpose_split_kernel(const float* __restrict__ X,
                                                              bf16_t* __restrict__ Fh,
                                                              bf16_t* __restrict__ Fl,
                                                              float* __restrict__ S1,
                                                              float* __restrict__ S2,
                                                              int pbase) {
    __shared__ float T[64][65];
    __shared__ float Ps[4][64], Ps2[4][64];
    int bb = blockIdx.z;
    int n0 = blockIdx.x * 64;
    int c0 = blockIdx.y * 64;
    const float* Xb = X + ((size_t)bb * CDIM) * HWN;
    int tid = threadIdx.x;
    int tx = tid & 63, ty = tid >> 6;
    #pragma unroll
    for (int cc = 0; cc < 64; cc += 4)
        T[cc + ty][tx] = Xb[(size_t)(c0 + cc + ty) * HWN + n0 + tx];
    __syncthreads();
    // per-pixel partial LN stats over this c-tile (4 threads/pixel)
    {
        float s = 0.f, s2 = 0.f;
        #pragma unroll
        for (int c = ty * 16; c < ty * 16 + 16; ++c) {
            float v = T[c][tx];
            s += v; s2 += v * v;
        }
        Ps[ty][tx] = s; Ps2[ty][tx] = s2;
    }
    __syncthreads();
    if (tid < 64) {
        float a = Ps[0][tid] + Ps[1][tid] + Ps[2][tid] + Ps[3][tid];
        float b = Ps2[0][tid] + Ps2[1][tid] + Ps2[2][tid] + Ps2[3][tid];
        int p = pbase + bb * HWN + n0 + tid;
        atomicAdd(&S1[p], a);
        atomicAdd(&S2[p], b);
    }
    // vectorized bf16x8 writes: 8 threads per n-row, 8 consecutive c each
    int nr = tid >> 3;            // 0..31
    int c8 = (tid & 7) << 3;      // 0..56
    size_t obase = ((size_t)bb * HWN) * CDIM;
    #pragma unroll
    for (int half = 0; half < 2; ++half) {
        int n = nr + 32 * half;
        bf16x8 hv, lv;
        #pragma unroll
        for (int j = 0; j < 8; ++j) {
            float v = T[c8 + j][n];
            bf16_t h = (bf16_t)v;
            hv[j] = h;
            lv[j] = (bf16_t)(v - (float)h);
        }
        size_t off = obase + (size_t)(n0 + n) * CDIM + c0 + c8;
        *(bf16x8*)&Fh[off] = hv;
        *(bf16x8*)&Fl[off] = lv;
    }
}

// ---------------- split-bf16 3-pass MFMA GEMM ----------------------------------------------------
// MODE 0 (QKV): grid.y = 6 -> path=y>>1, o-tile=y&1. Epilogue: input-LN from S1/S2 + wsum.
// MODE 1 (conv2): grid.y = MROWS/128. Epilogue: raw store + per-pixel sum/sumsq atomics into S1/S2.
template <int KDIM, int MROWS, int MODE>
__global__ __launch_bounds__(256) void mfma_gemm_kernel(const bf16_t* __restrict__ Wbase,
                                                        const bf16_t* __restrict__ Bh,
                                                        const bf16_t* __restrict__ Bl,
                                                        float* __restrict__ S1,
                                                        float* __restrict__ S2,
                                                        const float* __restrict__ wsum,
                                                        int pbase,
                                                        float* __restrict__ Ybase) {
    __shared__ bf16_t sA[2][128 * 32];
    __shared__ bf16_t sB[2][128 * 32];
    int bb = blockIdx.z;
    int n0 = blockIdx.x * 128;
    const int PS = INNER * CDIM;     // weight plane (bf16 elements)
    int o0, path;
    const bf16_t *Ah, *Al;
    float* Y;
    if (MODE == 0) {
        path = blockIdx.y >> 1;
        o0 = (blockIdx.y & 1) * 128;
        Ah = Wbase + (size_t)(2 * path) * PS;
        Al = Wbase + (size_t)(2 * path + 1) * PS;
        Y = Ybase + (size_t)path * PATHSZ;
        wsum += path * INNER;
    } else {
        path = 0;
        o0 = blockIdx.y * 128;
        Ah = Wbase;
        Al = Wbase + PS;
        Y = Ybase;
    }
    int tid = threadIdx.x;
    int wv = tid >> 6, ln = tid & 63;
    int wm = wv >> 1, wn = wv & 1;
    int quad = ln >> 4, lm = ln & 15;
    int srow = ln >> 2;
    int scol = (ln & 3) * 8;

    const bf16_t* Bhb = Bh + ((size_t)bb * HWN) * KDIM;
    const bf16_t* Blb = Bl + ((size_t)bb * HWN) * KDIM;

    f32x4 acc[4][4] = {};

    for (int c0 = 0; c0 < KDIM; c0 += 32) {
        __syncthreads();
        #pragma unroll
        for (int t = 0; t < 2; ++t) {
            int inst = wv * 2 + t;
            int row = inst * 16 + srow;
            size_t goA = (size_t)(o0 + row) * KDIM + c0 + scol;
            size_t goB = (size_t)(n0 + row) * KDIM + c0 + scol;
            load_lds16(&Ah[goA],  &sA[0][inst * 512]);
            load_lds16(&Al[goA],  &sA[1][inst * 512]);
            load_lds16(&Bhb[goB], &sB[0][inst * 512]);
            load_lds16(&Blb[goB], &sB[1][inst * 512]);
        }
        __syncthreads();

        bf16x8 afh[4], afl[4], bfh[4], bfl[4];
        #pragma unroll
        for (int i = 0; i < 4; ++i) {
            int o_l = wm * 64 + i * 16 + lm;
            afh[i] = *(const bf16x8*)&sA[0][o_l * 32 + quad * 8];
            afl[i] = *(const bf16x8*)&sA[1][o_l * 32 + quad * 8];
            int n_l = wn * 64 + i * 16 + lm;
            bfh[i] = *(const bf16x8*)&sB[0][n_l * 32 + quad * 8];
            bfl[i] = *(const bf16x8*)&sB[1][n_l * 32 + quad * 8];
        }
        #pragma unroll
        for (int i = 0; i < 4; ++i)
            #pragma unroll
            for (int j = 0; j < 4; ++j) {
                acc[i][j] = __builtin_amdgcn_mfma_f32_16x16x32_bf16(afh[i], bfh[j], acc[i][j], 0, 0, 0);
                acc[i][j] = __builtin_amdgcn_mfma_f32_16x16x32_bf16(afh[i], bfl[j], acc[i][j], 0, 0, 0);
                acc[i][j] = __builtin_amdgcn_mfma_f32_16x16x32_bf16(afl[i], bfh[j], acc[i][j], 0, 0, 0);
            }
    }

    float* Yb = Y + ((size_t)bb * MROWS) * HWN;
    __shared__ float Sn[128], Sn2[128];
    if (MODE == 1) {
        if (tid < 128) Sn[tid] = 0.f; else Sn2[tid - 128] = 0.f;
        __syncthreads();
    }
    #pragma unroll
    for (int j = 0; j < 4; ++j) {
        int nl = wn * 64 + j * 16 + lm;
        int n = n0 + nl;
        float mn = 0.f, rs = 0.f;
        if (MODE == 0) {
            int p = pbase + bb * HWN + n;
            float s1 = S1[p], s2 = S2[p];
            mn = s1 * (1.0f / CDIM);
            float var = s2 * (1.0f / CDIM) - mn * mn;
            rs = rsqrtf(var + EPSLN);
        }
        float js = 0.f, js2 = 0.f;
        #pragma unroll
        for (int i = 0; i < 4; ++i) {
            #pragma unroll
            for (int r = 0; r < 4; ++r) {
                int o = o0 + wm * 64 + i * 16 + quad * 4 + r;
                float v = acc[i][j][r];
                if (MODE == 0) v = rs * (v - mn * wsum[o]);
                Yb[(size_t)o * HWN + n] = v;
                if (MODE == 1) { js += v; js2 += v * v; }
            }
        }
        if (MODE == 1) {
            atomicAdd(&Sn[nl], js);
            atomicAdd(&Sn2[nl], js2);
        }
    }
    if (MODE == 1) {
        __syncthreads();
        if (tid < 128) {
            int p = pbase + bb * HWN + n0 + tid;
            atomicAdd(&S1[p], Sn[tid]);
            atomicAdd(&S2[p], Sn2[tid]);
        }
    }
}

// ---------------- merged depthwise 3x3 SAME, 3 paths; k-path fused exp + channel sums -----------
// A3/D3 layout: [path(q,k,v)][bb][c][HWN]. Each block = 256 consecutive n in one (path,bb,c).
__global__ __launch_bounds__(256) void dwconv_kernel(const float* __restrict__ A3,
                                                     const float* __restrict__ qwd,
                                                     const float* __restrict__ kwd,
                                                     const float* __restrict__ vwd,
                                                     float* __restrict__ D3,
                                                     float* __restrict__ Ssum,
                                                     int bo) {
    const int BPP = (int)(PATHSZ / 256);           // blocks per path = 36864
    int path = blockIdx.x / BPP;                   // block-uniform
    size_t li = (size_t)(blockIdx.x - path * BPP) * 256 + threadIdx.x;
    int n = (int)(li % HWN);
    int bc = (int)(li / HWN);
    int c = bc % INNER;
    int bb = bc / INNER;
    int y = n / WID, x = n % WID;
    const float* wf = ((path == 0) ? qwd : (path == 1) ? kwd : vwd) + c * 9;
    const float* base = A3 + (size_t)path * PATHSZ + (size_t)bc * HWN;
    float acc = 0.f;
    #pragma unroll
    for (int dy = 0; dy < 3; ++dy) {
        int yy = y + dy - 1;
        if ((unsigned)yy < HGT) {
            #pragma unroll
            for (int dx = 0; dx < 3; ++dx) {
                int xx = x + dx - 1;
                if ((unsigned)xx < WID) acc += base[yy * WID + xx] * wf[dy * 3 + dx];
            }
        }
    }
    size_t oi = (size_t)path * PATHSZ + li;
    if (path == 1) {
        float ev = __expf(acc);                    // no max-subtraction: |k| is O(1), safe in fp32
        D3[oi] = ev;
        __shared__ float red[256];
        int tid = threadIdx.x;
        red[tid] = ev;
        __syncthreads();
        for (int s = 128; s > 0; s >>= 1) {
            if (tid < s) red[tid] += red[tid + s];
            __syncthreads();
        }
        if (tid == 0) atomicAdd(&Ssum[(bo + bb) * INNER + c], red[0]);
    } else {
        D3[oi] = acc;
    }
}

// ---------------- context partials: ctxp[bh][seg][d][e] = sum_{n in seg} ek[d][n]*v[e][n] -------
__global__ __launch_bounds__(256) void context_kernel(const float* __restrict__ K,
                                                      const float* __restrict__ V,
                                                      float* __restrict__ ctxp) {
    int seg = blockIdx.x;                    // 0..15
    int bh = blockIdx.y;                     // 0..GB*NHEADS-1
    int bb = bh / NHEADS, h = bh % NHEADS;
    const float* kb = K + ((size_t)bb * INNER + h * DH) * HWN;
    const float* vb = V + ((size_t)bb * INNER + h * DH) * HWN;
    __shared__ float kt[DH][64];
    __shared__ float vt[DH][65];
    int tid = threadIdx.x;
    int e = tid & 31;
    int d0 = tid >> 5;
    float acc[4] = {0.f, 0.f, 0.f, 0.f};
    for (int ch = 0; ch < 9; ++ch) {
        int n0 = seg * 576 + ch * 64;
        __syncthreads();
        #pragma unroll
        for (int j = 0; j < 8; ++j) {
            int idx = tid + 256 * j;
            int d = idx >> 6, nn = idx & 63;
            kt[d][nn] = kb[(size_t)d * HWN + n0 + nn];
            vt[d][nn] = vb[(size_t)d * HWN + n0 + nn];
        }
        __syncthreads();
        for (int nn = 0; nn < 64; ++nn) {
            float vv = vt[e][nn];
            #pragma unroll
            for (int i = 0; i < 4; ++i) acc[i] += kt[d0 + 8 * i][nn] * vv;
        }
    }
    #pragma unroll
    for (int i = 0; i < 4; ++i)
        ctxp[(((size_t)bh * 16 + seg) * DH + d0 + 8 * i) * DH + e] = acc[i];
}

// ---------------- reduce ctxp over segs and fold in 1/sum(exp(k)) per (b, d-channel) ------------
__global__ __launch_bounds__(256) void ctxreduce_kernel(const float* __restrict__ ctxp,
                                                        const float* __restrict__ Ssum,
                                                        int bo,
                                                        float* __restrict__ ctx) {
    int i = blockIdx.x * 256 + threadIdx.x;  // over GB*NHEADS*1024
    int bh = i >> 10, de = i & 1023;
    int d = de >> 5;
    int bb = bh / NHEADS, h = bh % NHEADS;
    float s = 0.f;
    #pragma unroll
    for (int seg = 0; seg < 16; ++seg) s += ctxp[((size_t)bh * 16 + seg) * 1024 + de];
    float S = Ssum[(bo + bb) * INNER + h * DH + d];
    ctx[i] = s / S;
}

// ---------------- fused q-softmax + q@ctx + silu, writes Oh/Ol [bb][n][INNER] bf16 hi/lo --------
__global__ __launch_bounds__(256) void qctx_kernel(const float* __restrict__ Q,
                                                   const float* __restrict__ ctx,
                                                   bf16_t* __restrict__ Oh,
                                                   bf16_t* __restrict__ Ol) {
    int bh = blockIdx.y;
    int bb = bh / NHEADS, h = bh % NHEADS;
    int n = blockIdx.x * 256 + threadIdx.x;
    __shared__ float cs[DH * DH];
    for (int j = threadIdx.x; j < DH * DH; j += 256) cs[j] = ctx[(size_t)bh * DH * DH + j];
    __syncthreads();
    const float* qb = Q + ((size_t)bb * INNER + h * DH) * HWN + n;
    float qv[DH];
    float mx = -1e30f;
    #pragma unroll
    for (int d = 0; d < DH; ++d) { qv[d] = qb[(size_t)d * HWN]; mx = fmaxf(mx, qv[d]); }
    float s = 0.f;
    #pragma unroll
    for (int d = 0; d < DH; ++d) { qv[d] = __expf(qv[d] - mx); s += qv[d]; }
    float inv = QSCALE / s;
    float acc[DH];
    #pragma unroll
    for (int e = 0; e < DH; ++e) acc[e] = 0.f;
    #pragma unroll
    for (int d = 0; d < DH; ++d) {
        float q = qv[d] * inv;
        #pragma unroll
        for (int e = 0; e < DH; ++e) acc[e] += q * cs[d * DH + e];
    }
    size_t ob = ((size_t)bb * HWN + n) * INNER + h * DH;
    bf16x8 hv, lv;
    #pragma unroll
    for (int e8 = 0; e8 < 4; ++e8) {
        #pragma unroll
        for (int e = 0; e < 8; ++e) {
            float x = acc[e8 * 8 + e];
            float sl = x / (1.0f + __expf(-x));   // silu
            bf16_t h = (bf16_t)sl;
            hv[e] = h;
            lv[e] = (bf16_t)(sl - (float)h);
        }
        *(bf16x8*)&Oh[ob + e8 * 8] = hv;
        *(bf16x8*)&Ol[ob + e8 * 8] = lv;
    }
}

// ---------------- final normalize, stats from S1o/S2o accumulated by conv2 epilogue -------------
__global__ __launch_bounds__(256) void norm_kernel(const float* __restrict__ X,
                                                   const float* __restrict__ S1,
                                                   const float* __restrict__ S2,
                                                   const float* __restrict__ g,
                                                   float* __restrict__ out,
                                                   int pbase) {
    size_t i = (size_t)blockIdx.x * 256 + threadIdx.x;  // over GB*CDIM*HW
    int n = (int)(i % HWN);
    size_t bc = i / HWN;
    int c = (int)(bc % CDIM);
    int bb = (int)(bc / CDIM);
    int p = pbase + bb * HWN + n;
    float m = S1[p] * (1.0f / CDIM);
    float var = S2[p] * (1.0f / CDIM) - m * m;
    float rs = rsqrtf(var + EPSLN);
    out[i] = (X[i] - m) * rs * g[c];
}

extern "C" void kernel_launch(void* const* d_in, const int* in_sizes, int n_in,
                              void* d_out, int out_size, void* d_ws, size_t ws_size,
                              hipStream_t stream) {
    const float* fmap       = (const float*)d_in[0];
    const float* norm_g     = (const float*)d_in[1];
    const float* q_w1       = (const float*)d_in[2];
    const float* q_wd       = (const float*)d_in[3];
    const float* k_w1       = (const float*)d_in[4];
    const float* k_wd       = (const float*)d_in[5];
    const float* v_w1       = (const float*)d_in[6];
    const float* v_wd       = (const float*)d_in[7];
    const float* out_w      = (const float*)d_in[8];
    const float* out_norm_g = (const float*)d_in[9];
    float* out = (float*)d_out;

    float* ws = (float*)d_ws;
    size_t off = 0;
    auto alloc = [&](size_t n) { float* p = ws + off; off += n; return p; };
    // --- zeroed stats block (contiguous, one memset) ---
    float* S1   = alloc(73728);     // input-LN sum
    float* S2   = alloc(73728);     // input-LN sumsq
    float* S1o  = alloc(73728);     // output-LN sum (conv2 epilogue)
    float* S2o  = alloc(73728);     // output-LN sumsq
    float* Ssum = alloc(2048);      // per (b, inner-chan) sum of exp(k)
    const size_t ZERON = 73728ull * 4 + 2048;     // 296960 floats
    // --- rest ---
    float* wsum = alloc(768);
    bf16_t* WB  = (bf16_t*)alloc(393216);   // qkv weights, [3][hi/lo][131072] bf16
    bf16_t* OWB = (bf16_t*)alloc(131072);   // out_w, [hi/lo][131072] bf16
    float* ctxp = alloc(524288);
    float* ctx  = alloc(32768);
    bf16_t* Fh  = (bf16_t*)alloc(9437184);  // [GB][HWN][CDIM] bf16
    bf16_t* Fl  = (bf16_t*)alloc(9437184);
    float* A3   = alloc(3 * 9437184);       // [path][GB][INNER][HWN] fp32
    float* D3   = alloc(3 * 9437184);       // dwconv out (k-path holds exp)
    bf16_t* Oh  = (bf16_t*)alloc(4718592);  // [GB][HWN][INNER] bf16
    bf16_t* Ol  = (bf16_t*)alloc(4718592);
    float* CONV2 = alloc(18874368);         // [GB][CDIM][HWN] fp32
    // total: ~105.2M floats = 420.8 MB (ws is 576 MiB per harness fill size)

    dim3 blk(256);
    hipMemsetAsync(S1, 0, ZERON * sizeof(float), stream);
    wsum_kernel<<<dim3(3), blk, 0, stream>>>(q_w1, k_w1, v_w1, norm_g, wsum);
    wprep_kernel<<<dim3(2048), blk, 0, stream>>>(q_w1, k_w1, v_w1, norm_g, out_w, WB, OWB);

    for (int g = 0; g < 2; ++g) {
        const float* fmg = fmap + (size_t)g * GB * CDIM * HWN;
        int pbase = g * GB * HWN;
        int bo = g * GB;

        transpose_split_kernel<<<dim3(144, 8, GB), blk, 0, stream>>>(fmg, Fh, Fl, S1, S2, pbase);

        mfma_gemm_kernel<CDIM, INNER, 0><<<dim3(72, 6, GB), blk, 0, stream>>>(
            WB, Fh, Fl, S1, S2, wsum, pbase, A3);

        dwconv_kernel<<<dim3(3 * (int)(PATHSZ / 256)), blk, 0, stream>>>(
            A3, q_wd, k_wd, v_wd, D3, Ssum, bo);

        context_kernel<<<dim3(16, GB * NHEADS), blk, 0, stream>>>(
            D3 + PATHSZ, D3 + 2 * PATHSZ, ctxp);
        ctxreduce_kernel<<<dim3(GB * NHEADS * 1024 / 256), blk, 0, stream>>>(
            ctxp, Ssum, bo, ctx);
        qctx_kernel<<<dim3(HWN / 256, GB * NHEADS), blk, 0, stream>>>(D3, ctx, Oh, Ol);

        mfma_gemm_kernel<INNER, CDIM, 1><<<dim3(72, 4, GB), blk, 0, stream>>>(
            OWB, Oh, Ol, S1o, S2o, nullptr, pbase, CONV2);

        norm_kernel<<<dim3(GB * CDIM * HWN / 256), blk, 0, stream>>>(
            CONV2, S1o, S2o, out_norm_g, out + (size_t)g * GB * CDIM * HWN, pbase);
    }
}